// Round 20
// baseline (1875.964 us; speedup 1.0000x reference)
//
#include <hip/hip_runtime.h>
#include <cmath>

#define ROWS 8
#define THREADS 512
#define NB 2048
#define TSTEPS 128
#define DXF 409

using bf16   = __bf16;
using bf16x8 = __attribute__((ext_vector_type(8))) __bf16;
using bf16x4 = __attribute__((ext_vector_type(4))) __bf16;
using f32x4  = __attribute__((ext_vector_type(4))) float;

struct Params {
  const float *x;
  const float *Wl,*bWl,*Ul,*bUl,*Vl,*bVl;
  const float *Wa,*bWa,*Ua,*bUa,*Va,*bVa;
  const float *Wv,*bWv,*Uv,*bUv,*Vv,*bVv;
  const float *nlW1,*nlb1,*nlW2,*nlb2;
  const float *naW1,*nab1,*naW2,*nab2;
  const float *nvW1,*nvb1,*nvW2,*nvb2;
  const float *attW1,*attb1,*attW2,*attb2;
  const float *outW1,*outb1,*outW2,*outb2;
  const float *ws;
  float *out;
};

__device__ __forceinline__ float sigm(float x){ return 1.0f/(1.0f+__expf(-x)); }
__device__ __forceinline__ float ftanh(float x){
  x = fminf(fmaxf(x,-15.f),15.f);
  float e = __expf(2.f*x);
  return (e-1.f)/(e+1.f);
}

// ===== packed-weight offsets (bf16 elements) — layout verified in round 5 =====
#define OFF_Wl    0
#define OFF_Wa    163840
#define OFF_Wv    188416
#define OFF_Ul    204800
#define OFF_Vl    270336
#define OFF_Ua    303104
#define OFF_Va    319488
#define OFF_Uv    335872
#define OFF_Vv    352256
#define OFF_nlW1  368640
#define OFF_naW1  385024
#define OFF_nvW1  393216
#define OFF_attW1 401408
#define OFF_nlW2  434176
#define OFF_naW2  442368
#define OFF_nvW2  450560
#define OFF_attW2 458752
#define WS_ELEMS  460800
#define XWF_OFF   460800
#define XWF_ELEMS ((size_t)16384*64*64*4)

// ---- merged pack kernel ----
struct PackDesc { const float* src; int off, K, Kp, N, Np, blk0; };
struct PackArgs { PackDesc e[17]; bf16* dst; };

__global__ __launch_bounds__(256)
void pack_all(PackArgs A)
{
  const int bid = blockIdx.x;
  int ei = 0;
  for (int i=16;i>=0;i--){ if (bid >= A.e[i].blk0){ ei=i; break; } }
  const PackDesc d = A.e[ei];
  const int nKT = d.Kp >> 5;
  const int total = (d.Np >> 4) * nKT * 64;
  int idx = (bid - d.blk0)*256 + threadIdx.x;
  if (idx >= total) return;
  int lane = idx & 63;
  int tile = idx >> 6;
  int tn = tile / nKT, tk = tile - tn*nKT;
  int col = (tn<<4) + (lane & 15);
  int k0  = (tk<<5) + ((lane>>4)<<3);
  bf16x8 v;
  #pragma unroll
  for (int i=0;i<8;i++){
    int kr = k0 + i;
    float f = (kr < d.K && col < d.N) ? d.src[(size_t)kr*d.N + col] : 0.f;
    v[i] = (bf16)f;
  }
  ((bf16x8*)(A.dst + d.off))[idx] = v;
}

__device__ __forceinline__ f32x4 mfma16(bf16x8 a, bf16x8 b, f32x4 c){
  return __builtin_amdgcn_mfma_f32_16x16x32_bf16(a, b, c, 0, 0, 0);
}
__device__ __forceinline__ bf16x8 lda(const bf16* buf, int stride, int kt, int lane){
  return *(const bf16x8*)(buf + (lane&15)*stride + (kt<<5) + ((lane>>4)<<3));
}
__device__ __forceinline__ bf16x8 ldb(const bf16* base, int tile, int lane){
  return ((const bf16x8*)base)[tile*64 + lane];
}
__device__ __forceinline__ bf16x4 ldnt4(const bf16* p){
  return __builtin_nontemporal_load((const bf16x4*)p);
}

// ================= XW GEMM v2 (round-15 proven: regs-only, no LDS/barriers) =================
__global__ __launch_bounds__(256)
void xw_gemm2(const float* __restrict__ x, const bf16* __restrict__ wsb,
              bf16* __restrict__ xwf)
{
  const int tid=threadIdx.x, lane=tid&63, wave=tid>>6;
  const size_t mt = (size_t)blockIdx.x*4 + wave;
  const size_t row = mt*16 + (lane&15);
  const int k8 = ((lane>>4)<<3);
  const float* xr = x + row*DXF;

  bf16x8 aL[10], aA[3], aV[2];
  #pragma unroll
  for (int kt=0;kt<10;kt++){
    #pragma unroll
    for (int j=0;j<8;j++){
      int d = (kt<<5) + k8 + j;
      aL[kt][j] = (d<300) ? (bf16)xr[d] : (bf16)0.f;
    }
  }
  #pragma unroll
  for (int kt=0;kt<3;kt++){
    #pragma unroll
    for (int j=0;j<8;j++){
      int d = (kt<<5) + k8 + j;
      aA[kt][j] = (d<74) ? (bf16)xr[300+d] : (bf16)0.f;
    }
  }
  #pragma unroll
  for (int kt=0;kt<2;kt++){
    #pragma unroll
    for (int j=0;j<8;j++){
      int d = (kt<<5) + k8 + j;
      aV[kt][j] = (d<35) ? (bf16)xr[374+d] : (bf16)0.f;
    }
  }

  bf16* outb = xwf + (size_t)mt*64*64*4;

  #pragma unroll 2
  for (int nt=0;nt<32;nt++){
    f32x4 acc = {0,0,0,0};
    #pragma unroll
    for (int kt=0;kt<10;kt++) acc = mfma16(aL[kt], ldb(wsb+OFF_Wl, nt*10+kt, lane), acc);
    bf16x4 o;
    #pragma unroll
    for (int q=0;q<4;q++) o[q]=(bf16)acc[q];
    *(bf16x4*)(outb + ((size_t)nt*64 + lane)*4) = o;
  }
  #pragma unroll 2
  for (int tn=0;tn<16;tn++){
    f32x4 acc = {0,0,0,0};
    #pragma unroll
    for (int kt=0;kt<3;kt++) acc = mfma16(aA[kt], ldb(wsb+OFF_Wa, tn*3+kt, lane), acc);
    bf16x4 o;
    #pragma unroll
    for (int q=0;q<4;q++) o[q]=(bf16)acc[q];
    *(bf16x4*)(outb + ((size_t)(32+tn)*64 + lane)*4) = o;
  }
  #pragma unroll 2
  for (int tn=0;tn<16;tn++){
    f32x4 acc = {0,0,0,0};
    #pragma unroll
    for (int kt=0;kt<2;kt++) acc = mfma16(aV[kt], ldb(wsb+OFF_Wv, tn*2+kt, lane), acc);
    bf16x4 o;
    #pragma unroll
    for (int q=0;q<4;q++) o[q]=(bf16)acc[q];
    *(bf16x4*)(outb + ((size_t)(48+tn)*64 + lane)*4) = o;
  }
}

// ================= recurrent kernel: round-19 base + setprio on MFMA + bf16 sc* =================
__global__ __launch_bounds__(512, 1)
void tman_mfma3(Params p)
{
  __shared__ float attlog[16][4];
  __shared__ float blb[512], bab[256], bvb[256];
  __shared__ float b_nl1[128], b_na1[128], b_nv1[128], b_at1[128];
  __shared__ float b_nl2[64], b_na2[64], b_nv2[64], b_at2[4];
  __shared__ __align__(16) bf16 scl[16][72], sca[16][72], scv[16][72];   // bf16 (was fp32)
  __shared__ __align__(16) bf16 hl_b[2][16][136], cl_b[16][136];
  __shared__ __align__(16) bf16 ha_b[2][16][72], hv_b[2][16][72], ca_b[16][72], cv_b[16][72];
  __shared__ __align__(16) bf16 hidl_b[16][136], hida_b[16][136], hidv_b[16][136], hidat_b[16][136];
  __shared__ __align__(16) bf16 wst[8][8][512];    // attW1 frags: 64 KB (round-17 proven)
  __shared__ __align__(16) bf16 wst2[8][4][512];   // nlW1 frags: 32 KB (round-18 proven)

  const int tid=threadIdx.x, lane=tid&63, wave=tid>>6;
  const int rb=((lane>>4)<<2), cL=lane&15;
  const int b = ((blockIdx.x & 7) << 5) | (blockIdx.x >> 3);   // pair 2k,2k+1 -> same XCD
  const int n0 = b*ROWS;
  const int roff = (b&1)*8;
  const bool own = ((rb>>3) == (b&1));
  const int j2 = wave & 3;
  const bf16* wsb=(const bf16*)p.ws;
  const bf16* xwf=wsb + XWF_OFF;

  if (tid<512) blb[tid]=p.bWl[tid]+p.bUl[tid]+p.bVl[tid];
  if (tid<256){ bab[tid]=p.bWa[tid]+p.bUa[tid]+p.bVa[tid]; bvb[tid]=p.bWv[tid]+p.bUv[tid]+p.bVv[tid]; }
  if (tid<128){ b_nl1[tid]=p.nlb1[tid]; b_na1[tid]=p.nab1[tid]; b_nv1[tid]=p.nvb1[tid]; b_at1[tid]=p.attb1[tid]; }
  if (tid<64){ b_nl2[tid]=p.nlb2[tid]; b_na2[tid]=p.nab2[tid]; b_nv2[tid]=p.nvb2[tid]; }
  if (tid<4) b_at2[tid] = (tid<3) ? p.attb2[tid] : 0.f;
  for (int i=tid;i<2*16*136;i+=512) (&hl_b[0][0][0])[i]=(bf16)0.f;
  for (int i=tid;i<16*136;i+=512){
    (&cl_b[0][0])[i]=(bf16)0.f;
    (&hidl_b[0][0])[i]=(bf16)0.f; (&hida_b[0][0])[i]=(bf16)0.f;
    (&hidv_b[0][0])[i]=(bf16)0.f; (&hidat_b[0][0])[i]=(bf16)0.f;
  }
  for (int i=tid;i<2*16*72;i+=512){ (&ha_b[0][0][0])[i]=(bf16)0.f; (&hv_b[0][0][0])[i]=(bf16)0.f; }
  for (int i=tid;i<16*72;i+=512){
    (&ca_b[0][0])[i]=(bf16)0.f; (&cv_b[0][0])[i]=(bf16)0.f;
    (&scl[0][0])[i]=(bf16)0.f; (&sca[0][0])[i]=(bf16)0.f; (&scv[0][0])[i]=(bf16)0.f;
  }
  if (tid<64) attlog[tid>>2][tid&3]=0.f;

  float cregL[4] = {0.f,0.f,0.f,0.f};
  float creg2[4] = {0.f,0.f,0.f,0.f};

  // ---- gate weights (pre-loop regs, round-13 proven) ----
  bf16x8 wUl[4][4], wVl[4][2], wU2[4][2], wV2[4][2];
  bf16x8 d1s[4], d2s[8];
  #pragma unroll
  for (int g=0;g<4;g++){
    #pragma unroll
    for (int kt=0;kt<4;kt++) wUl[g][kt]=ldb(wsb+OFF_Ul,(g*8+wave)*4+kt,lane);
    #pragma unroll
    for (int kt=0;kt<2;kt++) wVl[g][kt]=ldb(wsb+OFF_Vl,(g*8+wave)*2+kt,lane);
  }
  {
    const int uoff = (wave<4)?OFF_Ua:OFF_Uv;
    const int voff = (wave<4)?OFF_Va:OFF_Vv;
    #pragma unroll
    for (int g=0;g<4;g++)
      #pragma unroll
      for (int kt=0;kt<2;kt++){
        wU2[g][kt]=ldb(wsb+uoff,(g*4+j2)*2+kt,lane);
        wV2[g][kt]=ldb(wsb+voff,(g*4+j2)*2+kt,lane);
      }
  }
  #pragma unroll
  for (int kt=0;kt<2;kt++) d1s[kt]  =ldb(wsb+OFF_naW1, wave*2+kt, lane);
  #pragma unroll
  for (int kt=0;kt<2;kt++) d1s[2+kt]=ldb(wsb+OFF_nvW1, wave*2+kt, lane);
  // ---- attW1 + nlW1 fragments -> LDS (once) ----
  #pragma unroll
  for (int kt=0;kt<8;kt++) *(bf16x8*)&wst[wave][kt][lane*8]  = ldb(wsb+OFF_attW1, wave*8+kt, lane);
  #pragma unroll
  for (int kt=0;kt<4;kt++) *(bf16x8*)&wst2[wave][kt][lane*8] = ldb(wsb+OFF_nlW1, wave*4+kt, lane);
  #pragma unroll
  for (int kt=0;kt<8;kt++) d2s[kt]=(bf16x8)(bf16)0.f;
  if (wave<4){
    #pragma unroll
    for (int kt=0;kt<4;kt++){ d2s[kt]=ldb(wsb+OFF_nlW2, wave*4+kt, lane);
                              d2s[4+kt]=ldb(wsb+OFF_nvW2, wave*4+kt, lane); }
  } else {
    #pragma unroll
    for (int kt=0;kt<4;kt++) d2s[kt]=ldb(wsb+OFF_naW2, (wave-4)*4+kt, lane);
    if (wave==7){
      #pragma unroll
      for (int kt=0;kt<4;kt++) d2s[4+kt]=ldb(wsb+OFF_attW2, kt, lane);
    }
  }
  __syncthreads();

  for (int t=0;t<TSTEPS;++t){
    const int cur = t & 1, nxt = cur ^ 1;
    const bf16* hlr = &hl_b[cur][0][0];
    const bf16* h2r = (wave<4) ? &ha_b[cur][0][0] : &hv_b[cur][0][0];
    const bf16* xwt = xwf + ((size_t)(t*128 + (b>>1)))*16384;

    bf16x4 xwL[4], xw2[4];
    #pragma unroll
    for (int g=0;g<4;g++){
      xwL[g] = ldnt4(xwt + ((size_t)(g*8+wave)*64+lane)*4);
      int nt2 = (wave<4) ? (32 + g*4 + j2) : (48 + g*4 + j2);
      xw2[g] = ldnt4(xwt + ((size_t)nt2*64+lane)*4);
    }

    bf16x8 az[2];
    {
      const int zr = lane & 15;
      float a0=attlog[zr][0], a1=attlog[zr][1], a2=attlog[zr][2];
      float m=fmaxf(a0,fmaxf(a1,a2));
      float e0=__expf(a0-m), e1=__expf(a1-m), e2=__expf(a2-m);
      float inv=1.f/(e0+e1+e2);
      e0*=inv; e1*=inv; e2*=inv;
      #pragma unroll
      for (int kt=0;kt<2;kt++){
        #pragma unroll
        for (int j=0;j<8;j++){
          int u = (kt<<5) + ((lane>>4)<<3) + j;
          az[kt][j] = (bf16)(e0*(float)scl[zr][u] + e1*(float)sca[zr][u] + e2*(float)scv[zr][u]);
        }
      }
    }

    f32x4 accL[4], acc2[4];
    #pragma unroll
    for (int g=0;g<4;g++){ accL[g]=(f32x4){0,0,0,0}; acc2[g]=(f32x4){0,0,0,0}; }

    __builtin_amdgcn_s_setprio(1);
    #pragma unroll
    for (int kt=0;kt<2;kt++){
      #pragma unroll
      for (int g=0;g<4;g++){ accL[g]=mfma16(az[kt],wVl[g][kt],accL[g]); acc2[g]=mfma16(az[kt],wV2[g][kt],acc2[g]); }
    }
    #pragma unroll
    for (int kt=0;kt<2;kt++){
      bf16x8 a = lda(h2r,72,kt,lane);
      #pragma unroll
      for (int g=0;g<4;g++) acc2[g]=mfma16(a,wU2[g][kt],acc2[g]);
    }
    #pragma unroll
    for (int kt=0;kt<4;kt++){
      bf16x8 a = lda(hlr,136,kt,lane);
      #pragma unroll
      for (int g=0;g<4;g++) accL[g]=mfma16(a,wUl[g][kt],accL[g]);
    }
    __builtin_amdgcn_s_setprio(0);

    {
      const int uL = (wave<<4)+cL;
      #pragma unroll
      for (int q=0;q<4;q++){
        const int row = rb+q;
        float f  = sigm (accL[0][q] + (float)xwL[0][q] + blb[uL]);
        float ig = sigm (accL[1][q] + (float)xwL[1][q] + blb[128+uL]);
        float o  = sigm (accL[2][q] + (float)xwL[2][q] + blb[256+uL]);
        float ch = ftanh(accL[3][q] + (float)xwL[3][q] + blb[384+uL]);
        float c = f*cregL[q] + ig*ch;
        float h = ftanh(c)*o;
        cregL[q]=c;
        if (own){ cl_b[row][uL]=(bf16)c; hl_b[nxt][row][uL]=(bf16)h; }
      }
      const int u2 = (j2<<4)+cL;
      const float* bb2 = (wave<4) ? bab : bvb;
      bf16 (*cb2)[72] = (wave<4) ? ca_b : cv_b;
      bf16 (*hb2)[72] = (wave<4) ? ha_b[nxt] : hv_b[nxt];
      #pragma unroll
      for (int q=0;q<4;q++){
        const int row = rb+q;
        float f  = sigm (acc2[0][q] + (float)xw2[0][q] + bb2[u2]);
        float ig = sigm (acc2[1][q] + (float)xw2[1][q] + bb2[64+u2]);
        float o  = sigm (acc2[2][q] + (float)xw2[2][q] + bb2[128+u2]);
        float ch = ftanh(acc2[3][q] + (float)xw2[3][q] + bb2[192+u2]);
        float c = f*creg2[q] + ig*ch;
        float h = ftanh(c)*o;
        creg2[q]=c;
        if (own){ cb2[row][u2]=(bf16)c; hb2[row][u2]=(bf16)h; }
      }
    }
    __syncthreads();   // bar2: new c visible

    __builtin_amdgcn_s_setprio(1);
    {
      f32x4 acc={0,0,0,0};
      #pragma unroll
      for (int kt=0;kt<4;kt++) acc=mfma16(lda(&cl_b[0][0],136,kt,lane),
                                          *(const bf16x8*)&wst2[wave][kt][lane*8], acc);
      const int col=wave*16+cL; const float bb=b_nl1[col];
      if (own){
        #pragma unroll
        for (int q=0;q<4;q++) hidl_b[rb+q][col]=(bf16)fmaxf(acc[q]+bb,0.f);
      }
    }
    {
      f32x4 acc={0,0,0,0};
      #pragma unroll
      for (int kt=0;kt<2;kt++) acc=mfma16(lda(&ca_b[0][0],72,kt,lane), d1s[kt], acc);
      const int col=wave*16+cL; const float bb=b_na1[col];
      if (own){
        #pragma unroll
        for (int q=0;q<4;q++) hida_b[rb+q][col]=(bf16)fmaxf(acc[q]+bb,0.f);
      }
    }
    {
      f32x4 acc={0,0,0,0};
      #pragma unroll
      for (int kt=0;kt<2;kt++) acc=mfma16(lda(&cv_b[0][0],72,kt,lane), d1s[2+kt], acc);
      const int col=wave*16+cL; const float bb=b_nv1[col];
      if (own){
        #pragma unroll
        for (int q=0;q<4;q++) hidv_b[rb+q][col]=(bf16)fmaxf(acc[q]+bb,0.f);
      }
    }
    {
      f32x4 acc={0,0,0,0};
      #pragma unroll
      for (int kt=0;kt<8;kt++){
        bf16x8 a = (kt<4) ? lda(&cl_b[0][0],136,kt,lane)
                 : (kt<6) ? lda(&ca_b[0][0],72,kt-4,lane)
                          : lda(&cv_b[0][0],72,kt-6,lane);
        acc=mfma16(a, *(const bf16x8*)&wst[wave][kt][lane*8], acc);
      }
      const int col=wave*16+cL; const float bb=b_at1[col];
      if (own){
        #pragma unroll
        for (int q=0;q<4;q++) hidat_b[rb+q][col]=(bf16)fmaxf(acc[q]+bb,0.f);
      }
    }
    __builtin_amdgcn_s_setprio(0);
    __syncthreads();   // bar3: hid* visible

    if (wave<4){
      f32x4 acc={0,0,0,0};
      #pragma unroll
      for (int kt=0;kt<4;kt++) acc=mfma16(lda(&hidl_b[0][0],136,kt,lane), d2s[kt], acc);
      const int col=wave*16+cL;
      { const float bb=b_nl2[col];
        if (own){
          #pragma unroll
          for (int q=0;q<4;q++) scl[rb+q][col]=(bf16)(acc[q]+bb);
        } }
      f32x4 accv={0,0,0,0};
      #pragma unroll
      for (int kt=0;kt<4;kt++) accv=mfma16(lda(&hidv_b[0][0],136,kt,lane), d2s[4+kt], accv);
      { const float bb=b_nv2[col];
        if (own){
          #pragma unroll
          for (int q=0;q<4;q++) scv[rb+q][col]=(bf16)(accv[q]+bb);
        } }
    } else {
      f32x4 acc={0,0,0,0};
      #pragma unroll
      for (int kt=0;kt<4;kt++) acc=mfma16(lda(&hida_b[0][0],136,kt,lane), d2s[kt], acc);
      const int col=(wave-4)*16+cL; const float bb=b_na2[col];
      if (own){
        #pragma unroll
        for (int q=0;q<4;q++) sca[rb+q][col]=(bf16)(acc[q]+bb);
      }
      if (wave==7){
        f32x4 acct={0,0,0,0};
        #pragma unroll
        for (int kt=0;kt<4;kt++) acct=mfma16(lda(&hidat_b[0][0],136,kt,lane), d2s[4+kt], acct);
        if (own && cL<3){
          #pragma unroll
          for (int q=0;q<4;q++) attlog[rb+q][cL]=acct[q]+b_at2[cL];
        }
      }
    }
    __syncthreads();   // bar4: sc*/attlog visible for next step
  }

  {
    const int r = roff + (tid>>6), u = tid&63;
    float a0=attlog[r][0], a1=attlog[r][1], a2=attlog[r][2];
    float m=fmaxf(a0,fmaxf(a1,a2));
    float e0=__expf(a0-m), e1=__expf(a1-m), e2=__expf(a2-m);
    float inv=1.f/(e0+e1+e2);
    cl_b[r][u] = (bf16)((e0*(float)scl[r][u]+e1*(float)sca[r][u]+e2*(float)scv[r][u])*inv);
  }
  __syncthreads();

  const int fin = TSTEPS & 1;
  if (tid<128){
    const int j=tid;
    float acc[8];
    #pragma unroll
    for (int r=0;r<8;r++) acc[r]=p.outb1[j];
    for (int k=0;k<128;k++){ float wv=p.outW1[k*128+j];
      #pragma unroll
      for (int r=0;r<8;r++) acc[r]=fmaf((float)hl_b[fin][roff+r][k],wv,acc[r]); }
    for (int k=0;k<64;k++){ float wv=p.outW1[(128+k)*128+j];
      #pragma unroll
      for (int r=0;r<8;r++) acc[r]=fmaf((float)ha_b[fin][roff+r][k],wv,acc[r]); }
    for (int k=0;k<64;k++){ float wv=p.outW1[(192+k)*128+j];
      #pragma unroll
      for (int r=0;r<8;r++) acc[r]=fmaf((float)hv_b[fin][roff+r][k],wv,acc[r]); }
    for (int k=0;k<64;k++){ float wv=p.outW1[(256+k)*128+j];
      #pragma unroll
      for (int r=0;r<8;r++) acc[r]=fmaf((float)cl_b[roff+r][k],wv,acc[r]); }
    #pragma unroll
    for (int r=0;r<8;r++) hidl_b[roff+r][j]=(bf16)fmaxf(acc[r],0.f);
  }
  __syncthreads();
  if (tid<8){
    float acc=p.outb2[0];
    for (int k=0;k<128;k++) acc=fmaf((float)hidl_b[roff+tid][k],p.outW2[k],acc);
    p.out[n0+tid]=acc;
  }
}

// ================= fallback: original fp32 kernel (proven, no-ws path) =================
template<int R,int COLS,int KDIM,int INSTRIDE>
__device__ __forceinline__ void acc_mm(const float* __restrict__ W,
                                       const float* __restrict__ in,
                                       float acc[R], int j)
{
  constexpr int K4 = KDIM/4;
  #pragma unroll 2
  for (int k4=0;k4<K4;k4++){
    const int k=4*k4;
    float w0=W[(k+0)*COLS+j];
    float w1=W[(k+1)*COLS+j];
    float w2=W[(k+2)*COLS+j];
    float w3=W[(k+3)*COLS+j];
    #pragma unroll
    for (int r=0;r<R;r++){
      const float4 v = *(const float4*)(in + r*INSTRIDE + k);
      acc[r]=fmaf(v.w,w3,fmaf(v.z,w2,fmaf(v.y,w1,fmaf(v.x,w0,acc[r]))));
    }
  }
  if constexpr ((KDIM & 3) != 0) {
    #pragma unroll
    for (int k=K4*4;k<KDIM;k++){
      float wv=W[k*COLS+j];
      #pragma unroll
      for (int r=0;r<R;r++) acc[r]=fmaf(in[r*INSTRIDE+k],wv,acc[r]);
    }
  }
}

__global__ __launch_bounds__(THREADS)
void tman_kernel(Params p)
{
  __shared__ float xsl[ROWS][300];
  __shared__ float xsa[ROWS][76];
  __shared__ float xsv[ROWS][36];
  __shared__ float cl[ROWS][128], hl[ROWS][128];
  __shared__ float ca[ROWS][64],  ha[ROWS][64];
  __shared__ float cv[ROWS][64],  hv[ROWS][64];
  __shared__ float zz[ROWS][64];
  __shared__ float sl[ROWS][512];
  __shared__ float sa[ROWS][256];
  __shared__ float sv[ROWS][256];
  __shared__ float hidl[ROWS][128], hida[ROWS][128], hidv[ROWS][128], hidat[ROWS][128];
  __shared__ float scl[ROWS][64], sca[ROWS][64], scv[ROWS][64];
  __shared__ float attlog[ROWS][4];
  __shared__ float bl[512], ba[256], bv[256];

  const int tid  = threadIdx.x;
  const int lane = tid & 63;
  const int wave = tid >> 6;
  const int n0   = blockIdx.x * ROWS;

  for (int i=tid;i<512;i+=THREADS) bl[i]=p.bWl[i]+p.bUl[i]+p.bVl[i];
  for (int i=tid;i<256;i+=THREADS){ ba[i]=p.bWa[i]+p.bUa[i]+p.bVa[i]; bv[i]=p.bWv[i]+p.bUv[i]+p.bVv[i]; }
  for (int i=tid;i<ROWS*128;i+=THREADS){ (&cl[0][0])[i]=0.f; (&hl[0][0])[i]=0.f; }
  for (int i=tid;i<ROWS*64;i+=THREADS){
    (&ca[0][0])[i]=0.f; (&ha[0][0])[i]=0.f;
    (&cv[0][0])[i]=0.f; (&hv[0][0])[i]=0.f;
    (&zz[0][0])[i]=0.f;
  }
  __syncthreads();

  for (int t=0;t<TSTEPS;++t){
    const float* xt = p.x + ((size_t)t*NB + n0)*DXF;
    for (int i=tid;i<ROWS*DXF;i+=THREADS){
      int r=i/DXF, d=i-r*DXF;
      float v=xt[(size_t)r*DXF+d];
      if (d<300) xsl[r][d]=v;
      else if (d<374) xsa[r][d-300]=v;
      else xsv[r][d-374]=v;
    }
    __syncthreads();

    {
      int j = wave*64 + lane;
      float acc[ROWS]; float b=bl[j];
      #pragma unroll
      for (int r=0;r<ROWS;r++) acc[r]=b;
      acc_mm<ROWS,512,300,300>(p.Wl,&xsl[0][0],acc,j);
      acc_mm<ROWS,512,128,128>(p.Ul,&hl[0][0],acc,j);
      acc_mm<ROWS,512, 64, 64>(p.Vl,&zz[0][0],acc,j);
      #pragma unroll
      for (int r=0;r<ROWS;r++) sl[r][j]=acc[r];
    }
    {
      int item = 15-wave;
      if (item>=12){
        int j=(item-12)*64+lane;
        float acc[ROWS]; float b=bv[j];
        #pragma unroll
        for (int r=0;r<ROWS;r++) acc[r]=b;
        acc_mm<ROWS,256,35,36>(p.Wv,&xsv[0][0],acc,j);
        acc_mm<ROWS,256,64,64>(p.Uv,&hv[0][0],acc,j);
        acc_mm<ROWS,256,64,64>(p.Vv,&zz[0][0],acc,j);
        #pragma unroll
        for (int r=0;r<ROWS;r++) sv[r][j]=acc[r];
      } else {
        int j=(item-8)*64+lane;
        float acc[ROWS]; float b=ba[j];
        #pragma unroll
        for (int r=0;r<ROWS;r++) acc[r]=b;
        acc_mm<ROWS,256,74,76>(p.Wa,&xsa[0][0],acc,j);
        acc_mm<ROWS,256,64,64>(p.Ua,&ha[0][0],acc,j);
        acc_mm<ROWS,256,64,64>(p.Va,&zz[0][0],acc,j);
        #pragma unroll
        for (int r=0;r<ROWS;r++) sa[r][j]=acc[r];
      }
    }
    __syncthreads();

    for (int i=tid;i<ROWS*128;i+=THREADS){
      int r=i>>7, u=i&127;
      float f =sigm(sl[r][u]);
      float ig=sigm(sl[r][128+u]);
      float o =sigm(sl[r][256+u]);
      float ch=tanhf(sl[r][384+u]);
      float c=f*cl[r][u]+ig*ch;
      cl[r][u]=c; hl[r][u]=tanhf(c)*o;
    }
    for (int i=tid;i<ROWS*64;i+=THREADS){
      int r=i>>6, u=i&63;
      { float f=sigm(sa[r][u]), ig=sigm(sa[r][64+u]), o=sigm(sa[r][128+u]), ch=tanhf(sa[r][192+u]);
        float c=f*ca[r][u]+ig*ch; ca[r][u]=c; ha[r][u]=tanhf(c)*o; }
      { float f=sigm(sv[r][u]), ig=sigm(sv[r][64+u]), o=sigm(sv[r][128+u]), ch=tanhf(sv[r][192+u]);
        float c=f*cv[r][u]+ig*ch; cv[r][u]=c; hv[r][u]=tanhf(c)*o; }
    }
    __syncthreads();

    if (wave<2){
      int j=wave*64+lane;
      float acc[ROWS]; float b=p.nlb1[j];
      #pragma unroll
      for (int r=0;r<ROWS;r++) acc[r]=b;
      acc_mm<ROWS,128,128,128>(p.nlW1,&cl[0][0],acc,j);
      #pragma unroll
      for (int r=0;r<ROWS;r++) hidl[r][j]=fmaxf(acc[r],0.f);
    } else if (wave<4){
      int j=(wave-2)*64+lane;
      float acc[ROWS]; float b=p.nab1[j];
      #pragma unroll
      for (int r=0;r<ROWS;r++) acc[r]=b;
      acc_mm<ROWS,128,64,64>(p.naW1,&ca[0][0],acc,j);
      #pragma unroll
      for (int r=0;r<ROWS;r++) hida[r][j]=fmaxf(acc[r],0.f);
    } else if (wave<6){
      int j=(wave-4)*64+lane;
      float acc[ROWS]; float b=p.nvb1[j];
      #pragma unroll
      for (int r=0;r<ROWS;r++) acc[r]=b;
      acc_mm<ROWS,128,64,64>(p.nvW1,&cv[0][0],acc,j);
      #pragma unroll
      for (int r=0;r<ROWS;r++) hidv[r][j]=fmaxf(acc[r],0.f);
    } else {
      int j=(wave-6)*64+lane;
      float acc[ROWS]; float b=p.attb1[j];
      #pragma unroll
      for (int r=0;r<ROWS;r++) acc[r]=b;
      acc_mm<ROWS,128,128,128>(p.attW1,          &cl[0][0],acc,j);
      acc_mm<ROWS,128, 64, 64>(p.attW1+128*128,  &ca[0][0],acc,j);
      acc_mm<ROWS,128, 64, 64>(p.attW1+192*128,  &cv[0][0],acc,j);
      #pragma unroll
      for (int r=0;r<ROWS;r++) hidat[r][j]=fmaxf(acc[r],0.f);
    }
    __syncthreads();

    if (wave==0){
      float acc[ROWS]; float b=p.nlb2[lane];
      #pragma unroll
      for (int r=0;r<ROWS;r++) acc[r]=b;
      acc_mm<ROWS,64,128,128>(p.nlW2,&hidl[0][0],acc,lane);
      #pragma unroll
      for (int r=0;r<ROWS;r++) scl[r][lane]=acc[r];
    } else if (wave==1){
      float acc[ROWS]; float b=p.nab2[lane];
      #pragma unroll
      for (int r=0;r<ROWS;r++) acc[r]=b;
      acc_mm<ROWS,64,128,128>(p.naW2,&hida[0][0],acc,lane);
      #pragma unroll
      for (int r=0;r<ROWS;r++) sca[r][lane]=acc[r];
    } else if (wave==2){
      float acc[ROWS]; float b=p.nvb2[lane];
      #pragma unroll
      for (int r=0;r<ROWS;r++) acc[r]=b;
      acc_mm<ROWS,64,128,128>(p.nvW2,&hidv[0][0],acc,lane);
      #pragma unroll
      for (int r=0;r<ROWS;r++) scv[r][lane]=acc[r];
    } else if (wave==3 && lane<ROWS*3){
      int r=lane/3, m=lane-3*r;
      float a=p.attb2[m];
      for (int k=0;k<128;k++) a=fmaf(hidat[r][k],p.attW2[k*3+m],a);
      attlog[r][m]=a;
    }
    __syncthreads();

    for (int i=tid;i<ROWS*64;i+=THREADS){
      int r=i>>6, u=i&63;
      float a0=attlog[r][0], a1=attlog[r][1], a2=attlog[r][2];
      float m=fmaxf(a0,fmaxf(a1,a2));
      float e0=__expf(a0-m), e1=__expf(a1-m), e2=__expf(a2-m);
      float inv=1.f/(e0+e1+e2);
      zz[r][u]=(e0*scl[r][u]+e1*sca[r][u]+e2*scv[r][u])*inv;
    }
    __syncthreads();
  }

  if (wave<2){
    int j=wave*64+lane;
    float acc[ROWS]; float b=p.outb1[j];
    #pragma unroll
    for (int r=0;r<ROWS;r++) acc[r]=b;
    acc_mm<ROWS,128,128,128>(p.outW1,          &hl[0][0],acc,j);
    acc_mm<ROWS,128, 64, 64>(p.outW1+128*128,  &ha[0][0],acc,j);
    acc_mm<ROWS,128, 64, 64>(p.outW1+192*128,  &hv[0][0],acc,j);
    acc_mm<ROWS,128, 64, 64>(p.outW1+256*128,  &zz[0][0],acc,j);
    #pragma unroll
    for (int r=0;r<ROWS;r++) hidl[r][j]=fmaxf(acc[r],0.f);
  }
  __syncthreads();
  if (tid<ROWS){
    float acc=p.outb2[0];
    for (int k=0;k<128;k++) acc=fmaf(hidl[tid][k],p.outW2[k],acc);
    p.out[n0+tid]=acc;
  }
}

extern "C" void kernel_launch(void* const* d_in, const int* in_sizes, int n_in,
                              void* d_out, int out_size, void* d_ws, size_t ws_size,
                              hipStream_t stream) {
  const float* const* f = (const float* const*)d_in;
  Params P;
  P.x  =f[0];
  P.Wl =f[1];  P.bWl=f[2];  P.Ul =f[3];  P.bUl=f[4];  P.Vl =f[5];  P.bVl=f[6];
  P.Wa =f[7];  P.bWa=f[8];  P.Ua =f[9];  P.bUa=f[10]; P.Va =f[11]; P.bVa=f[12];
  P.Wv =f[13]; P.bWv=f[14]; P.Uv =f[15]; P.bUv=f[16]; P.Vv =f[17]; P.bVv=f[18];
  P.nlW1=f[19]; P.nlb1=f[20]; P.nlW2=f[21]; P.nlb2=f[22];
  P.naW1=f[23]; P.nab1=f[24]; P.naW2=f[25]; P.nab2=f[26];
  P.nvW1=f[27]; P.nvb1=f[28]; P.nvW2=f[29]; P.nvb2=f[30];
  P.attW1=f[31]; P.attb1=f[32]; P.attW2=f[33]; P.attb2=f[34];
  P.outW1=f[35]; P.outb1=f[36]; P.outW2=f[37]; P.outb2=f[38];
  P.out=(float*)d_out;
  P.ws =(const float*)d_ws;

  const size_t WS_NEED = ((size_t)WS_ELEMS + XWF_ELEMS) * sizeof(bf16);  // ~513 MB
  if (ws_size >= WS_NEED) {
    bf16* wsb = (bf16*)d_ws;
    PackArgs A;
    struct Pk { int src; int off, K, Kp, N, Np; } pk[17] = {
      {  1, OFF_Wl,   300, 320, 512, 512 },
      {  7, OFF_Wa,    74,  96, 256, 256 },
      { 13, OFF_Wv,    35,  64, 256, 256 },
      {  3, OFF_Ul,   128, 128, 512, 512 },
      {  5, OFF_Vl,    64,  64, 512, 512 },
      {  9, OFF_Ua,    64,  64, 256, 256 },
      { 11, OFF_Va,    64,  64, 256, 256 },
      { 15, OFF_Uv,    64,  64, 256, 256 },
      { 17, OFF_Vv,    64,  64, 256, 256 },
      { 19, OFF_nlW1, 128, 128, 128, 128 },
      { 23, OFF_naW1,  64,  64, 128, 128 },
      { 27, OFF_nvW1,  64,  64, 128, 128 },
      { 31, OFF_attW1,256, 256, 128, 128 },
      { 21, OFF_nlW2, 128, 128,  64,  64 },
      { 25, OFF_naW2, 128, 128,  64,  64 },
      { 29, OFF_nvW2, 128, 128,  64,  64 },
      { 33, OFF_attW2,128, 128,   3,  16 },
    };
    int blk = 0;
    for (int i=0;i<17;i++){
      int total = (pk[i].Np>>4) * (pk[i].Kp>>5) * 64;
      A.e[i].src = f[pk[i].src];
      A.e[i].off = pk[i].off; A.e[i].K = pk[i].K; A.e[i].Kp = pk[i].Kp;
      A.e[i].N = pk[i].N; A.e[i].Np = pk[i].Np; A.e[i].blk0 = blk;
      blk += (total + 255)/256;
    }
    A.dst = wsb;
    hipLaunchKernelGGL(pack_all, dim3(blk), dim3(256), 0, stream, A);
    hipLaunchKernelGGL(xw_gemm2, dim3(TSTEPS*NB/64), dim3(256), 0, stream,
                       P.x, wsb, wsb + XWF_OFF);
    hipLaunchKernelGGL(tman_mfma3, dim3(NB/ROWS), dim3(512), 0, stream, P);
  } else {
    hipLaunchKernelGGL(tman_kernel, dim3(NB/ROWS), dim3(THREADS), 0, stream, P);
  }
}

// Round 21
// 1772.986 us; speedup vs baseline: 1.0581x; 1.0581x over previous
//
#include <hip/hip_runtime.h>
#include <cmath>

#define ROWS 8
#define THREADS 512
#define NB 2048
#define TSTEPS 128
#define DXF 409

using bf16   = __bf16;
using bf16x8 = __attribute__((ext_vector_type(8))) __bf16;
using bf16x4 = __attribute__((ext_vector_type(4))) __bf16;
using f32x4  = __attribute__((ext_vector_type(4))) float;

struct Params {
  const float *x;
  const float *Wl,*bWl,*Ul,*bUl,*Vl,*bVl;
  const float *Wa,*bWa,*Ua,*bUa,*Va,*bVa;
  const float *Wv,*bWv,*Uv,*bUv,*Vv,*bVv;
  const float *nlW1,*nlb1,*nlW2,*nlb2;
  const float *naW1,*nab1,*naW2,*nab2;
  const float *nvW1,*nvb1,*nvW2,*nvb2;
  const float *attW1,*attb1,*attW2,*attb2;
  const float *outW1,*outb1,*outW2,*outb2;
  const float *ws;
  float *out;
};

__device__ __forceinline__ float sigm(float x){ return 1.0f/(1.0f+__expf(-x)); }
__device__ __forceinline__ float ftanh(float x){
  x = fminf(fmaxf(x,-15.f),15.f);
  float e = __expf(2.f*x);
  return (e-1.f)/(e+1.f);
}

// ===== packed-weight offsets (bf16 elements) — layout verified in round 5 =====
#define OFF_Wl    0
#define OFF_Wa    163840
#define OFF_Wv    188416
#define OFF_Ul    204800
#define OFF_Vl    270336
#define OFF_Ua    303104
#define OFF_Va    319488
#define OFF_Uv    335872
#define OFF_Vv    352256
#define OFF_nlW1  368640
#define OFF_naW1  385024
#define OFF_nvW1  393216
#define OFF_attW1 401408
#define OFF_nlW2  434176
#define OFF_naW2  442368
#define OFF_nvW2  450560
#define OFF_attW2 458752
#define WS_ELEMS  460800
#define XWF_OFF   460800
#define XWF_ELEMS ((size_t)16384*64*64*4)

// ---- merged pack kernel ----
struct PackDesc { const float* src; int off, K, Kp, N, Np, blk0; };
struct PackArgs { PackDesc e[17]; bf16* dst; };

__global__ __launch_bounds__(256)
void pack_all(PackArgs A)
{
  const int bid = blockIdx.x;
  int ei = 0;
  for (int i=16;i>=0;i--){ if (bid >= A.e[i].blk0){ ei=i; break; } }
  const PackDesc d = A.e[ei];
  const int nKT = d.Kp >> 5;
  const int total = (d.Np >> 4) * nKT * 64;
  int idx = (bid - d.blk0)*256 + threadIdx.x;
  if (idx >= total) return;
  int lane = idx & 63;
  int tile = idx >> 6;
  int tn = tile / nKT, tk = tile - tn*nKT;
  int col = (tn<<4) + (lane & 15);
  int k0  = (tk<<5) + ((lane>>4)<<3);
  bf16x8 v;
  #pragma unroll
  for (int i=0;i<8;i++){
    int kr = k0 + i;
    float f = (kr < d.K && col < d.N) ? d.src[(size_t)kr*d.N + col] : 0.f;
    v[i] = (bf16)f;
  }
  ((bf16x8*)(A.dst + d.off))[idx] = v;
}

__device__ __forceinline__ f32x4 mfma16(bf16x8 a, bf16x8 b, f32x4 c){
  return __builtin_amdgcn_mfma_f32_16x16x32_bf16(a, b, c, 0, 0, 0);
}
__device__ __forceinline__ bf16x8 lda(const bf16* buf, int stride, int kt, int lane){
  return *(const bf16x8*)(buf + (lane&15)*stride + (kt<<5) + ((lane>>4)<<3));
}
__device__ __forceinline__ bf16x8 ldb(const bf16* base, int tile, int lane){
  return ((const bf16x8*)base)[tile*64 + lane];
}
__device__ __forceinline__ bf16x4 ldnt4(const bf16* p){
  return __builtin_nontemporal_load((const bf16x4*)p);
}

// ================= XW GEMM v2 (round-15 proven: regs-only, no LDS/barriers) =================
__global__ __launch_bounds__(256)
void xw_gemm2(const float* __restrict__ x, const bf16* __restrict__ wsb,
              bf16* __restrict__ xwf)
{
  const int tid=threadIdx.x, lane=tid&63, wave=tid>>6;
  const size_t mt = (size_t)blockIdx.x*4 + wave;
  const size_t row = mt*16 + (lane&15);
  const int k8 = ((lane>>4)<<3);
  const float* xr = x + row*DXF;

  bf16x8 aL[10], aA[3], aV[2];
  #pragma unroll
  for (int kt=0;kt<10;kt++){
    #pragma unroll
    for (int j=0;j<8;j++){
      int d = (kt<<5) + k8 + j;
      aL[kt][j] = (d<300) ? (bf16)xr[d] : (bf16)0.f;
    }
  }
  #pragma unroll
  for (int kt=0;kt<3;kt++){
    #pragma unroll
    for (int j=0;j<8;j++){
      int d = (kt<<5) + k8 + j;
      aA[kt][j] = (d<74) ? (bf16)xr[300+d] : (bf16)0.f;
    }
  }
  #pragma unroll
  for (int kt=0;kt<2;kt++){
    #pragma unroll
    for (int j=0;j<8;j++){
      int d = (kt<<5) + k8 + j;
      aV[kt][j] = (d<35) ? (bf16)xr[374+d] : (bf16)0.f;
    }
  }

  bf16* outb = xwf + (size_t)mt*64*64*4;

  #pragma unroll 2
  for (int nt=0;nt<32;nt++){
    f32x4 acc = {0,0,0,0};
    #pragma unroll
    for (int kt=0;kt<10;kt++) acc = mfma16(aL[kt], ldb(wsb+OFF_Wl, nt*10+kt, lane), acc);
    bf16x4 o;
    #pragma unroll
    for (int q=0;q<4;q++) o[q]=(bf16)acc[q];
    *(bf16x4*)(outb + ((size_t)nt*64 + lane)*4) = o;
  }
  #pragma unroll 2
  for (int tn=0;tn<16;tn++){
    f32x4 acc = {0,0,0,0};
    #pragma unroll
    for (int kt=0;kt<3;kt++) acc = mfma16(aA[kt], ldb(wsb+OFF_Wa, tn*3+kt, lane), acc);
    bf16x4 o;
    #pragma unroll
    for (int q=0;q<4;q++) o[q]=(bf16)acc[q];
    *(bf16x4*)(outb + ((size_t)(32+tn)*64 + lane)*4) = o;
  }
  #pragma unroll 2
  for (int tn=0;tn<16;tn++){
    f32x4 acc = {0,0,0,0};
    #pragma unroll
    for (int kt=0;kt<2;kt++) acc = mfma16(aV[kt], ldb(wsb+OFF_Wv, tn*2+kt, lane), acc);
    bf16x4 o;
    #pragma unroll
    for (int q=0;q<4;q++) o[q]=(bf16)acc[q];
    *(bf16x4*)(outb + ((size_t)(48+tn)*64 + lane)*4) = o;
  }
}

// ================= recurrent kernel: round-19 EXACT (best: 1450 us / total 1774 us) =================
__global__ __launch_bounds__(512, 1)
void tman_mfma3(Params p)
{
  __shared__ float scl[16][68], sca[16][68], scv[16][68];
  __shared__ float attlog[16][4];
  __shared__ float blb[512], bab[256], bvb[256];
  __shared__ float b_nl1[128], b_na1[128], b_nv1[128], b_at1[128];
  __shared__ float b_nl2[64], b_na2[64], b_nv2[64], b_at2[4];
  __shared__ __align__(16) bf16 hl_b[2][16][136], cl_b[16][136];
  __shared__ __align__(16) bf16 ha_b[2][16][72], hv_b[2][16][72], ca_b[16][72], cv_b[16][72];
  __shared__ __align__(16) bf16 hidl_b[16][136], hida_b[16][136], hidv_b[16][136], hidat_b[16][136];
  __shared__ __align__(16) bf16 wst[8][8][512];    // attW1 frags: 64 KB (round-17 proven)
  __shared__ __align__(16) bf16 wst2[8][4][512];   // nlW1 frags: 32 KB (round-18 proven)

  const int tid=threadIdx.x, lane=tid&63, wave=tid>>6;
  const int rb=((lane>>4)<<2), cL=lane&15;
  const int b = ((blockIdx.x & 7) << 5) | (blockIdx.x >> 3);   // pair 2k,2k+1 -> same XCD
  const int n0 = b*ROWS;
  const int roff = (b&1)*8;
  const bool own = ((rb>>3) == (b&1));
  const int j2 = wave & 3;
  const bf16* wsb=(const bf16*)p.ws;
  const bf16* xwf=wsb + XWF_OFF;

  if (tid<512) blb[tid]=p.bWl[tid]+p.bUl[tid]+p.bVl[tid];
  if (tid<256){ bab[tid]=p.bWa[tid]+p.bUa[tid]+p.bVa[tid]; bvb[tid]=p.bWv[tid]+p.bUv[tid]+p.bVv[tid]; }
  if (tid<128){ b_nl1[tid]=p.nlb1[tid]; b_na1[tid]=p.nab1[tid]; b_nv1[tid]=p.nvb1[tid]; b_at1[tid]=p.attb1[tid]; }
  if (tid<64){ b_nl2[tid]=p.nlb2[tid]; b_na2[tid]=p.nab2[tid]; b_nv2[tid]=p.nvb2[tid]; }
  if (tid<4) b_at2[tid] = (tid<3) ? p.attb2[tid] : 0.f;
  for (int i=tid;i<2*16*136;i+=512) (&hl_b[0][0][0])[i]=(bf16)0.f;
  for (int i=tid;i<16*136;i+=512){
    (&cl_b[0][0])[i]=(bf16)0.f;
    (&hidl_b[0][0])[i]=(bf16)0.f; (&hida_b[0][0])[i]=(bf16)0.f;
    (&hidv_b[0][0])[i]=(bf16)0.f; (&hidat_b[0][0])[i]=(bf16)0.f;
  }
  for (int i=tid;i<2*16*72;i+=512){ (&ha_b[0][0][0])[i]=(bf16)0.f; (&hv_b[0][0][0])[i]=(bf16)0.f; }
  for (int i=tid;i<16*72;i+=512){ (&ca_b[0][0])[i]=(bf16)0.f; (&cv_b[0][0])[i]=(bf16)0.f; }
  for (int i=tid;i<16*68;i+=512){ (&scl[0][0])[i]=0.f; (&sca[0][0])[i]=0.f; (&scv[0][0])[i]=0.f; }
  if (tid<64) attlog[tid>>2][tid&3]=0.f;

  float cregL[4] = {0.f,0.f,0.f,0.f};
  float creg2[4] = {0.f,0.f,0.f,0.f};

  // ---- gate weights (pre-loop regs, round-13 proven) ----
  bf16x8 wUl[4][4], wVl[4][2], wU2[4][2], wV2[4][2];
  bf16x8 d1s[4], d2s[8];
  #pragma unroll
  for (int g=0;g<4;g++){
    #pragma unroll
    for (int kt=0;kt<4;kt++) wUl[g][kt]=ldb(wsb+OFF_Ul,(g*8+wave)*4+kt,lane);
    #pragma unroll
    for (int kt=0;kt<2;kt++) wVl[g][kt]=ldb(wsb+OFF_Vl,(g*8+wave)*2+kt,lane);
  }
  {
    const int uoff = (wave<4)?OFF_Ua:OFF_Uv;
    const int voff = (wave<4)?OFF_Va:OFF_Vv;
    #pragma unroll
    for (int g=0;g<4;g++)
      #pragma unroll
      for (int kt=0;kt<2;kt++){
        wU2[g][kt]=ldb(wsb+uoff,(g*4+j2)*2+kt,lane);
        wV2[g][kt]=ldb(wsb+voff,(g*4+j2)*2+kt,lane);
      }
  }
  #pragma unroll
  for (int kt=0;kt<2;kt++) d1s[kt]  =ldb(wsb+OFF_naW1, wave*2+kt, lane);
  #pragma unroll
  for (int kt=0;kt<2;kt++) d1s[2+kt]=ldb(wsb+OFF_nvW1, wave*2+kt, lane);
  // ---- attW1 + nlW1 fragments -> LDS (once) ----
  #pragma unroll
  for (int kt=0;kt<8;kt++) *(bf16x8*)&wst[wave][kt][lane*8]  = ldb(wsb+OFF_attW1, wave*8+kt, lane);
  #pragma unroll
  for (int kt=0;kt<4;kt++) *(bf16x8*)&wst2[wave][kt][lane*8] = ldb(wsb+OFF_nlW1, wave*4+kt, lane);
  #pragma unroll
  for (int kt=0;kt<8;kt++) d2s[kt]=(bf16x8)(bf16)0.f;
  if (wave<4){
    #pragma unroll
    for (int kt=0;kt<4;kt++){ d2s[kt]=ldb(wsb+OFF_nlW2, wave*4+kt, lane);
                              d2s[4+kt]=ldb(wsb+OFF_nvW2, wave*4+kt, lane); }
  } else {
    #pragma unroll
    for (int kt=0;kt<4;kt++) d2s[kt]=ldb(wsb+OFF_naW2, (wave-4)*4+kt, lane);
    if (wave==7){
      #pragma unroll
      for (int kt=0;kt<4;kt++) d2s[4+kt]=ldb(wsb+OFF_attW2, kt, lane);
    }
  }
  __syncthreads();

  for (int t=0;t<TSTEPS;++t){
    const int cur = t & 1, nxt = cur ^ 1;
    const bf16* hlr = &hl_b[cur][0][0];
    const bf16* h2r = (wave<4) ? &ha_b[cur][0][0] : &hv_b[cur][0][0];
    const bf16* xwt = xwf + ((size_t)(t*128 + (b>>1)))*16384;

    bf16x4 xwL[4], xw2[4];
    #pragma unroll
    for (int g=0;g<4;g++){
      xwL[g] = ldnt4(xwt + ((size_t)(g*8+wave)*64+lane)*4);
      int nt2 = (wave<4) ? (32 + g*4 + j2) : (48 + g*4 + j2);
      xw2[g] = ldnt4(xwt + ((size_t)nt2*64+lane)*4);
    }

    bf16x8 az[2];
    {
      const int zr = lane & 15;
      float a0=attlog[zr][0], a1=attlog[zr][1], a2=attlog[zr][2];
      float m=fmaxf(a0,fmaxf(a1,a2));
      float e0=__expf(a0-m), e1=__expf(a1-m), e2=__expf(a2-m);
      float inv=1.f/(e0+e1+e2);
      e0*=inv; e1*=inv; e2*=inv;
      #pragma unroll
      for (int kt=0;kt<2;kt++){
        #pragma unroll
        for (int j=0;j<8;j++){
          int u = (kt<<5) + ((lane>>4)<<3) + j;
          az[kt][j] = (bf16)(e0*scl[zr][u] + e1*sca[zr][u] + e2*scv[zr][u]);
        }
      }
    }

    f32x4 accL[4], acc2[4];
    #pragma unroll
    for (int g=0;g<4;g++){ accL[g]=(f32x4){0,0,0,0}; acc2[g]=(f32x4){0,0,0,0}; }

    #pragma unroll
    for (int kt=0;kt<2;kt++){
      #pragma unroll
      for (int g=0;g<4;g++){ accL[g]=mfma16(az[kt],wVl[g][kt],accL[g]); acc2[g]=mfma16(az[kt],wV2[g][kt],acc2[g]); }
    }
    #pragma unroll
    for (int kt=0;kt<2;kt++){
      bf16x8 a = lda(h2r,72,kt,lane);
      #pragma unroll
      for (int g=0;g<4;g++) acc2[g]=mfma16(a,wU2[g][kt],acc2[g]);
    }
    #pragma unroll
    for (int kt=0;kt<4;kt++){
      bf16x8 a = lda(hlr,136,kt,lane);
      #pragma unroll
      for (int g=0;g<4;g++) accL[g]=mfma16(a,wUl[g][kt],accL[g]);
    }

    {
      const int uL = (wave<<4)+cL;
      #pragma unroll
      for (int q=0;q<4;q++){
        const int row = rb+q;
        float f  = sigm (accL[0][q] + (float)xwL[0][q] + blb[uL]);
        float ig = sigm (accL[1][q] + (float)xwL[1][q] + blb[128+uL]);
        float o  = sigm (accL[2][q] + (float)xwL[2][q] + blb[256+uL]);
        float ch = ftanh(accL[3][q] + (float)xwL[3][q] + blb[384+uL]);
        float c = f*cregL[q] + ig*ch;
        float h = ftanh(c)*o;
        cregL[q]=c;
        if (own){ cl_b[row][uL]=(bf16)c; hl_b[nxt][row][uL]=(bf16)h; }
      }
      const int u2 = (j2<<4)+cL;
      const float* bb2 = (wave<4) ? bab : bvb;
      bf16 (*cb2)[72] = (wave<4) ? ca_b : cv_b;
      bf16 (*hb2)[72] = (wave<4) ? ha_b[nxt] : hv_b[nxt];
      #pragma unroll
      for (int q=0;q<4;q++){
        const int row = rb+q;
        float f  = sigm (acc2[0][q] + (float)xw2[0][q] + bb2[u2]);
        float ig = sigm (acc2[1][q] + (float)xw2[1][q] + bb2[64+u2]);
        float o  = sigm (acc2[2][q] + (float)xw2[2][q] + bb2[128+u2]);
        float ch = ftanh(acc2[3][q] + (float)xw2[3][q] + bb2[192+u2]);
        float c = f*creg2[q] + ig*ch;
        float h = ftanh(c)*o;
        creg2[q]=c;
        if (own){ cb2[row][u2]=(bf16)c; hb2[row][u2]=(bf16)h; }
      }
    }
    __syncthreads();   // bar2: new c visible

    {
      f32x4 acc={0,0,0,0};
      #pragma unroll
      for (int kt=0;kt<4;kt++) acc=mfma16(lda(&cl_b[0][0],136,kt,lane),
                                          *(const bf16x8*)&wst2[wave][kt][lane*8], acc);
      const int col=wave*16+cL; const float bb=b_nl1[col];
      if (own){
        #pragma unroll
        for (int q=0;q<4;q++) hidl_b[rb+q][col]=(bf16)fmaxf(acc[q]+bb,0.f);
      }
    }
    {
      f32x4 acc={0,0,0,0};
      #pragma unroll
      for (int kt=0;kt<2;kt++) acc=mfma16(lda(&ca_b[0][0],72,kt,lane), d1s[kt], acc);
      const int col=wave*16+cL; const float bb=b_na1[col];
      if (own){
        #pragma unroll
        for (int q=0;q<4;q++) hida_b[rb+q][col]=(bf16)fmaxf(acc[q]+bb,0.f);
      }
    }
    {
      f32x4 acc={0,0,0,0};
      #pragma unroll
      for (int kt=0;kt<2;kt++) acc=mfma16(lda(&cv_b[0][0],72,kt,lane), d1s[2+kt], acc);
      const int col=wave*16+cL; const float bb=b_nv1[col];
      if (own){
        #pragma unroll
        for (int q=0;q<4;q++) hidv_b[rb+q][col]=(bf16)fmaxf(acc[q]+bb,0.f);
      }
    }
    {
      f32x4 acc={0,0,0,0};
      #pragma unroll
      for (int kt=0;kt<8;kt++){
        bf16x8 a = (kt<4) ? lda(&cl_b[0][0],136,kt,lane)
                 : (kt<6) ? lda(&ca_b[0][0],72,kt-4,lane)
                          : lda(&cv_b[0][0],72,kt-6,lane);
        acc=mfma16(a, *(const bf16x8*)&wst[wave][kt][lane*8], acc);
      }
      const int col=wave*16+cL; const float bb=b_at1[col];
      if (own){
        #pragma unroll
        for (int q=0;q<4;q++) hidat_b[rb+q][col]=(bf16)fmaxf(acc[q]+bb,0.f);
      }
    }
    __syncthreads();   // bar3: hid* visible

    if (wave<4){
      f32x4 acc={0,0,0,0};
      #pragma unroll
      for (int kt=0;kt<4;kt++) acc=mfma16(lda(&hidl_b[0][0],136,kt,lane), d2s[kt], acc);
      const int col=wave*16+cL;
      { const float bb=b_nl2[col];
        if (own){
          #pragma unroll
          for (int q=0;q<4;q++) scl[rb+q][col]=acc[q]+bb;
        } }
      f32x4 accv={0,0,0,0};
      #pragma unroll
      for (int kt=0;kt<4;kt++) accv=mfma16(lda(&hidv_b[0][0],136,kt,lane), d2s[4+kt], accv);
      { const float bb=b_nv2[col];
        if (own){
          #pragma unroll
          for (int q=0;q<4;q++) scv[rb+q][col]=accv[q]+bb;
        } }
    } else {
      f32x4 acc={0,0,0,0};
      #pragma unroll
      for (int kt=0;kt<4;kt++) acc=mfma16(lda(&hida_b[0][0],136,kt,lane), d2s[kt], acc);
      const int col=(wave-4)*16+cL; const float bb=b_na2[col];
      if (own){
        #pragma unroll
        for (int q=0;q<4;q++) sca[rb+q][col]=acc[q]+bb;
      }
      if (wave==7){
        f32x4 acct={0,0,0,0};
        #pragma unroll
        for (int kt=0;kt<4;kt++) acct=mfma16(lda(&hidat_b[0][0],136,kt,lane), d2s[4+kt], acct);
        if (own && cL<3){
          #pragma unroll
          for (int q=0;q<4;q++) attlog[rb+q][cL]=acct[q]+b_at2[cL];
        }
      }
    }
    __syncthreads();   // bar4: sc*/attlog visible for next step
  }

  {
    const int r = roff + (tid>>6), u = tid&63;
    float a0=attlog[r][0], a1=attlog[r][1], a2=attlog[r][2];
    float m=fmaxf(a0,fmaxf(a1,a2));
    float e0=__expf(a0-m), e1=__expf(a1-m), e2=__expf(a2-m);
    float inv=1.f/(e0+e1+e2);
    cl_b[r][u] = (bf16)((e0*scl[r][u]+e1*sca[r][u]+e2*scv[r][u])*inv);
  }
  __syncthreads();

  const int fin = TSTEPS & 1;
  if (tid<128){
    const int j=tid;
    float acc[8];
    #pragma unroll
    for (int r=0;r<8;r++) acc[r]=p.outb1[j];
    for (int k=0;k<128;k++){ float wv=p.outW1[k*128+j];
      #pragma unroll
      for (int r=0;r<8;r++) acc[r]=fmaf((float)hl_b[fin][roff+r][k],wv,acc[r]); }
    for (int k=0;k<64;k++){ float wv=p.outW1[(128+k)*128+j];
      #pragma unroll
      for (int r=0;r<8;r++) acc[r]=fmaf((float)ha_b[fin][roff+r][k],wv,acc[r]); }
    for (int k=0;k<64;k++){ float wv=p.outW1[(192+k)*128+j];
      #pragma unroll
      for (int r=0;r<8;r++) acc[r]=fmaf((float)hv_b[fin][roff+r][k],wv,acc[r]); }
    for (int k=0;k<64;k++){ float wv=p.outW1[(256+k)*128+j];
      #pragma unroll
      for (int r=0;r<8;r++) acc[r]=fmaf((float)cl_b[roff+r][k],wv,acc[r]); }
    #pragma unroll
    for (int r=0;r<8;r++){
      float hd = fmaxf(acc[r],0.f);
      if (j<64) scl[roff+r][j]=hd; else sca[roff+r][j-64]=hd;
    }
  }
  __syncthreads();
  if (tid<8){
    float acc=p.outb2[0];
    for (int k=0;k<64;k++)   acc=fmaf(scl[roff+tid][k],p.outW2[k],acc);
    for (int k=64;k<128;k++) acc=fmaf(sca[roff+tid][k-64],p.outW2[k],acc);
    p.out[n0+tid]=acc;
  }
}

// ================= fallback: original fp32 kernel (proven, no-ws path) =================
template<int R,int COLS,int KDIM,int INSTRIDE>
__device__ __forceinline__ void acc_mm(const float* __restrict__ W,
                                       const float* __restrict__ in,
                                       float acc[R], int j)
{
  constexpr int K4 = KDIM/4;
  #pragma unroll 2
  for (int k4=0;k4<K4;k4++){
    const int k=4*k4;
    float w0=W[(k+0)*COLS+j];
    float w1=W[(k+1)*COLS+j];
    float w2=W[(k+2)*COLS+j];
    float w3=W[(k+3)*COLS+j];
    #pragma unroll
    for (int r=0;r<R;r++){
      const float4 v = *(const float4*)(in + r*INSTRIDE + k);
      acc[r]=fmaf(v.w,w3,fmaf(v.z,w2,fmaf(v.y,w1,fmaf(v.x,w0,acc[r]))));
    }
  }
  if constexpr ((KDIM & 3) != 0) {
    #pragma unroll
    for (int k=K4*4;k<KDIM;k++){
      float wv=W[k*COLS+j];
      #pragma unroll
      for (int r=0;r<R;r++) acc[r]=fmaf(in[r*INSTRIDE+k],wv,acc[r]);
    }
  }
}

__global__ __launch_bounds__(THREADS)
void tman_kernel(Params p)
{
  __shared__ float xsl[ROWS][300];
  __shared__ float xsa[ROWS][76];
  __shared__ float xsv[ROWS][36];
  __shared__ float cl[ROWS][128], hl[ROWS][128];
  __shared__ float ca[ROWS][64],  ha[ROWS][64];
  __shared__ float cv[ROWS][64],  hv[ROWS][64];
  __shared__ float zz[ROWS][64];
  __shared__ float sl[ROWS][512];
  __shared__ float sa[ROWS][256];
  __shared__ float sv[ROWS][256];
  __shared__ float hidl[ROWS][128], hida[ROWS][128], hidv[ROWS][128], hidat[ROWS][128];
  __shared__ float scl[ROWS][64], sca[ROWS][64], scv[ROWS][64];
  __shared__ float attlog[ROWS][4];
  __shared__ float bl[512], ba[256], bv[256];

  const int tid  = threadIdx.x;
  const int lane = tid & 63;
  const int wave = tid >> 6;
  const int n0   = blockIdx.x * ROWS;

  for (int i=tid;i<512;i+=THREADS) bl[i]=p.bWl[i]+p.bUl[i]+p.bVl[i];
  for (int i=tid;i<256;i+=THREADS){ ba[i]=p.bWa[i]+p.bUa[i]+p.bVa[i]; bv[i]=p.bWv[i]+p.bUv[i]+p.bVv[i]; }
  for (int i=tid;i<ROWS*128;i+=THREADS){ (&cl[0][0])[i]=0.f; (&hl[0][0])[i]=0.f; }
  for (int i=tid;i<ROWS*64;i+=THREADS){
    (&ca[0][0])[i]=0.f; (&ha[0][0])[i]=0.f;
    (&cv[0][0])[i]=0.f; (&hv[0][0])[i]=0.f;
    (&zz[0][0])[i]=0.f;
  }
  __syncthreads();

  for (int t=0;t<TSTEPS;++t){
    const float* xt = p.x + ((size_t)t*NB + n0)*DXF;
    for (int i=tid;i<ROWS*DXF;i+=THREADS){
      int r=i/DXF, d=i-r*DXF;
      float v=xt[(size_t)r*DXF+d];
      if (d<300) xsl[r][d]=v;
      else if (d<374) xsa[r][d-300]=v;
      else xsv[r][d-374]=v;
    }
    __syncthreads();

    {
      int j = wave*64 + lane;
      float acc[ROWS]; float b=bl[j];
      #pragma unroll
      for (int r=0;r<ROWS;r++) acc[r]=b;
      acc_mm<ROWS,512,300,300>(p.Wl,&xsl[0][0],acc,j);
      acc_mm<ROWS,512,128,128>(p.Ul,&hl[0][0],acc,j);
      acc_mm<ROWS,512, 64, 64>(p.Vl,&zz[0][0],acc,j);
      #pragma unroll
      for (int r=0;r<ROWS;r++) sl[r][j]=acc[r];
    }
    {
      int item = 15-wave;
      if (item>=12){
        int j=(item-12)*64+lane;
        float acc[ROWS]; float b=bv[j];
        #pragma unroll
        for (int r=0;r<ROWS;r++) acc[r]=b;
        acc_mm<ROWS,256,35,36>(p.Wv,&xsv[0][0],acc,j);
        acc_mm<ROWS,256,64,64>(p.Uv,&hv[0][0],acc,j);
        acc_mm<ROWS,256,64,64>(p.Vv,&zz[0][0],acc,j);
        #pragma unroll
        for (int r=0;r<ROWS;r++) sv[r][j]=acc[r];
      } else {
        int j=(item-8)*64+lane;
        float acc[ROWS]; float b=ba[j];
        #pragma unroll
        for (int r=0;r<ROWS;r++) acc[r]=b;
        acc_mm<ROWS,256,74,76>(p.Wa,&xsa[0][0],acc,j);
        acc_mm<ROWS,256,64,64>(p.Ua,&ha[0][0],acc,j);
        acc_mm<ROWS,256,64,64>(p.Va,&zz[0][0],acc,j);
        #pragma unroll
        for (int r=0;r<ROWS;r++) sa[r][j]=acc[r];
      }
    }
    __syncthreads();

    for (int i=tid;i<ROWS*128;i+=THREADS){
      int r=i>>7, u=i&127;
      float f =sigm(sl[r][u]);
      float ig=sigm(sl[r][128+u]);
      float o =sigm(sl[r][256+u]);
      float ch=tanhf(sl[r][384+u]);
      float c=f*cl[r][u]+ig*ch;
      cl[r][u]=c; hl[r][u]=tanhf(c)*o;
    }
    for (int i=tid;i<ROWS*64;i+=THREADS){
      int r=i>>6, u=i&63;
      { float f=sigm(sa[r][u]), ig=sigm(sa[r][64+u]), o=sigm(sa[r][128+u]), ch=tanhf(sa[r][192+u]);
        float c=f*ca[r][u]+ig*ch; ca[r][u]=c; ha[r][u]=tanhf(c)*o; }
      { float f=sigm(sv[r][u]), ig=sigm(sv[r][64+u]), o=sigm(sv[r][128+u]), ch=tanhf(sv[r][192+u]);
        float c=f*cv[r][u]+ig*ch; cv[r][u]=c; hv[r][u]=tanhf(c)*o; }
    }
    __syncthreads();

    if (wave<2){
      int j=wave*64+lane;
      float acc[ROWS]; float b=p.nlb1[j];
      #pragma unroll
      for (int r=0;r<ROWS;r++) acc[r]=b;
      acc_mm<ROWS,128,128,128>(p.nlW1,&cl[0][0],acc,j);
      #pragma unroll
      for (int r=0;r<ROWS;r++) hidl[r][j]=fmaxf(acc[r],0.f);
    } else if (wave<4){
      int j=(wave-2)*64+lane;
      float acc[ROWS]; float b=p.nab1[j];
      #pragma unroll
      for (int r=0;r<ROWS;r++) acc[r]=b;
      acc_mm<ROWS,128,64,64>(p.naW1,&ca[0][0],acc,j);
      #pragma unroll
      for (int r=0;r<ROWS;r++) hida[r][j]=fmaxf(acc[r],0.f);
    } else if (wave<6){
      int j=(wave-4)*64+lane;
      float acc[ROWS]; float b=p.nvb1[j];
      #pragma unroll
      for (int r=0;r<ROWS;r++) acc[r]=b;
      acc_mm<ROWS,128,64,64>(p.nvW1,&cv[0][0],acc,j);
      #pragma unroll
      for (int r=0;r<ROWS;r++) hidv[r][j]=fmaxf(acc[r],0.f);
    } else {
      int j=(wave-6)*64+lane;
      float acc[ROWS]; float b=p.attb1[j];
      #pragma unroll
      for (int r=0;r<ROWS;r++) acc[r]=b;
      acc_mm<ROWS,128,128,128>(p.attW1,          &cl[0][0],acc,j);
      acc_mm<ROWS,128, 64, 64>(p.attW1+128*128,  &ca[0][0],acc,j);
      acc_mm<ROWS,128, 64, 64>(p.attW1+192*128,  &cv[0][0],acc,j);
      #pragma unroll
      for (int r=0;r<ROWS;r++) hidat[r][j]=fmaxf(acc[r],0.f);
    }
    __syncthreads();

    if (wave==0){
      float acc[ROWS]; float b=p.nlb2[lane];
      #pragma unroll
      for (int r=0;r<ROWS;r++) acc[r]=b;
      acc_mm<ROWS,64,128,128>(p.nlW2,&hidl[0][0],acc,lane);
      #pragma unroll
      for (int r=0;r<ROWS;r++) scl[r][lane]=acc[r];
    } else if (wave==1){
      float acc[ROWS]; float b=p.nab2[lane];
      #pragma unroll
      for (int r=0;r<ROWS;r++) acc[r]=b;
      acc_mm<ROWS,64,128,128>(p.naW2,&hida[0][0],acc,lane);
      #pragma unroll
      for (int r=0;r<ROWS;r++) sca[r][lane]=acc[r];
    } else if (wave==2){
      float acc[ROWS]; float b=p.nvb2[lane];
      #pragma unroll
      for (int r=0;r<ROWS;r++) acc[r]=b;
      acc_mm<ROWS,64,128,128>(p.nvW2,&hidv[0][0],acc,lane);
      #pragma unroll
      for (int r=0;r<ROWS;r++) scv[r][lane]=acc[r];
    } else if (wave==3 && lane<ROWS*3){
      int r=lane/3, m=lane-3*r;
      float a=p.attb2[m];
      for (int k=0;k<128;k++) a=fmaf(hidat[r][k],p.attW2[k*3+m],a);
      attlog[r][m]=a;
    }
    __syncthreads();

    for (int i=tid;i<ROWS*64;i+=THREADS){
      int r=i>>6, u=i&63;
      float a0=attlog[r][0], a1=attlog[r][1], a2=attlog[r][2];
      float m=fmaxf(a0,fmaxf(a1,a2));
      float e0=__expf(a0-m), e1=__expf(a1-m), e2=__expf(a2-m);
      float inv=1.f/(e0+e1+e2);
      zz[r][u]=(e0*scl[r][u]+e1*sca[r][u]+e2*scv[r][u])*inv;
    }
    __syncthreads();
  }

  if (wave<2){
    int j=wave*64+lane;
    float acc[ROWS]; float b=p.outb1[j];
    #pragma unroll
    for (int r=0;r<ROWS;r++) acc[r]=b;
    acc_mm<ROWS,128,128,128>(p.outW1,          &hl[0][0],acc,j);
    acc_mm<ROWS,128, 64, 64>(p.outW1+128*128,  &ha[0][0],acc,j);
    acc_mm<ROWS,128, 64, 64>(p.outW1+192*128,  &hv[0][0],acc,j);
    acc_mm<ROWS,128, 64, 64>(p.outW1+256*128,  &zz[0][0],acc,j);
    #pragma unroll
    for (int r=0;r<ROWS;r++) hidl[r][j]=fmaxf(acc[r],0.f);
  }
  __syncthreads();
  if (tid<ROWS){
    float acc=p.outb2[0];
    for (int k=0;k<128;k++) acc=fmaf(hidl[tid][k],p.outW2[k],acc);
    p.out[n0+tid]=acc;
  }
}

extern "C" void kernel_launch(void* const* d_in, const int* in_sizes, int n_in,
                              void* d_out, int out_size, void* d_ws, size_t ws_size,
                              hipStream_t stream) {
  const float* const* f = (const float* const*)d_in;
  Params P;
  P.x  =f[0];
  P.Wl =f[1];  P.bWl=f[2];  P.Ul =f[3];  P.bUl=f[4];  P.Vl =f[5];  P.bVl=f[6];
  P.Wa =f[7];  P.bWa=f[8];  P.Ua =f[9];  P.bUa=f[10]; P.Va =f[11]; P.bVa=f[12];
  P.Wv =f[13]; P.bWv=f[14]; P.Uv =f[15]; P.bUv=f[16]; P.Vv =f[17]; P.bVv=f[18];
  P.nlW1=f[19]; P.nlb1=f[20]; P.nlW2=f[21]; P.nlb2=f[22];
  P.naW1=f[23]; P.nab1=f[24]; P.naW2=f[25]; P.nab2=f[26];
  P.nvW1=f[27]; P.nvb1=f[28]; P.nvW2=f[29]; P.nvb2=f[30];
  P.attW1=f[31]; P.attb1=f[32]; P.attW2=f[33]; P.attb2=f[34];
  P.outW1=f[35]; P.outb1=f[36]; P.outW2=f[37]; P.outb2=f[38];
  P.out=(float*)d_out;
  P.ws =(const float*)d_ws;

  const size_t WS_NEED = ((size_t)WS_ELEMS + XWF_ELEMS) * sizeof(bf16);  // ~513 MB
  if (ws_size >= WS_NEED) {
    bf16* wsb = (bf16*)d_ws;
    PackArgs A;
    struct Pk { int src; int off, K, Kp, N, Np; } pk[17] = {
      {  1, OFF_Wl,   300, 320, 512, 512 },
      {  7, OFF_Wa,    74,  96, 256, 256 },
      { 13, OFF_Wv,    35,  64, 256, 256 },
      {  3, OFF_Ul,   128, 128, 512, 512 },
      {  5, OFF_Vl,    64,  64, 512, 512 },
      {  9, OFF_Ua,    64,  64, 256, 256 },
      { 11, OFF_Va,    64,  64, 256, 256 },
      { 15, OFF_Uv,    64,  64, 256, 256 },
      { 17, OFF_Vv,    64,  64, 256, 256 },
      { 19, OFF_nlW1, 128, 128, 128, 128 },
      { 23, OFF_naW1,  64,  64, 128, 128 },
      { 27, OFF_nvW1,  64,  64, 128, 128 },
      { 31, OFF_attW1,256, 256, 128, 128 },
      { 21, OFF_nlW2, 128, 128,  64,  64 },
      { 25, OFF_naW2, 128, 128,  64,  64 },
      { 29, OFF_nvW2, 128, 128,  64,  64 },
      { 33, OFF_attW2,128, 128,   3,  16 },
    };
    int blk = 0;
    for (int i=0;i<17;i++){
      int total = (pk[i].Np>>4) * (pk[i].Kp>>5) * 64;
      A.e[i].src = f[pk[i].src];
      A.e[i].off = pk[i].off; A.e[i].K = pk[i].K; A.e[i].Kp = pk[i].Kp;
      A.e[i].N = pk[i].N; A.e[i].Np = pk[i].Np; A.e[i].blk0 = blk;
      blk += (total + 255)/256;
    }
    A.dst = wsb;
    hipLaunchKernelGGL(pack_all, dim3(blk), dim3(256), 0, stream, A);
    hipLaunchKernelGGL(xw_gemm2, dim3(TSTEPS*NB/64), dim3(256), 0, stream,
                       P.x, wsb, wsb + XWF_OFF);
    hipLaunchKernelGGL(tman_mfma3, dim3(NB/ROWS), dim3(512), 0, stream, P);
  } else {
    hipLaunchKernelGGL(tman_kernel, dim3(NB/ROWS), dim3(THREADS), 0, stream, P);
  }
}